// Round 10
// baseline (77.088 us; speedup 1.0000x reference)
//
#include <hip/hip_runtime.h>

// Performer causal linear attention (generalized relu kernel), fp32 in/out.
// B=1, H=8, N=1024, D=64, M=128. Sub-block formulation, S=32 rows/block:
//   qp = relu(norm * q @ proj^T) + eps ; kp likewise
//   Z  = cumsum_n kp ; W = qp / Z
//   out_s = W_s @ S0_s + tril(W_s @ Kp_s^T) @ V_s ; S0_s = prefix of Kp^T V
// R22 = R21 resubmitted (round 9 was an infra failure, no signal).
// R21: 2 blocks/CU for the two big kernels (were 256 blocks = 1/CU: when all
// 8 waves hit a barrier waiting on ~900cy staged loads, the CU idles — R16
// measured 3-4% VALUBusy in these bodies). k_projg splits by M-half
// (grid 32x8x2, 256 thr); k_attn splits by e-half (grid 256x2, 256 thr;
// z-scan+P1 duplicated per half — they were idle-wave phases; both halves
// of (h,s) land on the same CU -> L1 reuse of kp/qp). Per-element
// arithmetic identical; z-scan carry is 2-lane (positive-sum reassoc,
// same class as R18). k_prefix unchanged (proven latency-insensitive, R20).
static constexpr int H = 8, N = 1024, D = 64, M = 128;
static constexpr float EPS = 1e-3f;
static constexpr float NORM = 0.35355339059327373f; // 64^-0.25

typedef __attribute__((ext_vector_type(8))) short short8;
typedef __attribute__((ext_vector_type(4))) float f32x4;

__device__ inline unsigned short f2bf(float x) {
    unsigned u = __float_as_uint(x);
    return (unsigned short)((u + 0x7fffu + ((u >> 16) & 1u)) >> 16);
}
__device__ inline float bf2f(unsigned short u) {
    return __uint_as_float(((unsigned)u) << 16);
}
__device__ inline ushort4 pack4(float4 g) {
    return (ushort4){f2bf(g.x), f2bf(g.y), f2bf(g.z), f2bf(g.w)};
}

// -------- K1 (R21): grid (32 rblk, 8 h, 2 mhf), 256 thr. One block:
// 32 rows of q AND k, M-half (64 cols) of qp/kp/G/kpart.
__global__ __launch_bounds__(256) void k_projg(const float* __restrict__ q,
                                               const float* __restrict__ k,
                                               const float* __restrict__ proj,
                                               const float* __restrict__ v,
                                               unsigned short* __restrict__ qpb,
                                               unsigned short* __restrict__ kpb,
                                               unsigned short* __restrict__ Gpb,
                                               float* __restrict__ kpart) {
    __shared__ __align__(16) short smem[18944]; // 37.9 KB -> 2 blocks/CU
    short* projb = smem;         // [m_l 64][72] B-operand (half of proj)
    short* xb = smem + 4608;     // [r 64][72] A-operand (q rows 0-31, k 32-63)
    short* obuf = smem + 9216;   // [64][72] out tile / later G [64][68]
    short* kpT = smem + 13824;   // [m_l 64][40] A-operand for G
    short* vT = smem + 16384;    // [e 64][40] B-operand for G
    const int tid = threadIdx.x;
    const int rblk = blockIdx.x;
    const int h = blockIdx.y;
    const int mhf = blockIdx.z;
    const int rowbase = h * N + rblk * 32;
    const int lane = tid & 63, wv = tid >> 6; // wv = rt (0..3)
    const int rt = wv;
    const int fr = lane & 15, fq = lane >> 4;

    // ---- front-load q/k/v loads, then proj half
    {
        int r = tid >> 3, dq2 = (tid & 7) * 2;
#pragma unroll
        for (int t = 0; t < 2; t++) {
            int dq = dq2 + t;
            float4 g = *(const float4*)&q[(rowbase + r) * D + dq * 4];
            float4 gk = *(const float4*)&k[(rowbase + r) * D + dq * 4];
            g.x *= NORM; g.y *= NORM; g.z *= NORM; g.w *= NORM;
            *(ushort4*)&xb[r * 72 + dq * 4] = pack4(g);
            gk.x *= NORM; gk.y *= NORM; gk.z *= NORM; gk.w *= NORM;
            *(ushort4*)&xb[(32 + r) * 72 + dq * 4] = pack4(gk);
        }
        int rv = tid & 31, e8 = (tid >> 5) * 8;
#pragma unroll
        for (int t = 0; t < 2; t++) {
            int e4 = e8 + t * 4;
            float4 gv = *(const float4*)&v[(rowbase + rv) * D + e4];
            vT[(e4 + 0) * 40 + rv] = (short)f2bf(gv.x);
            vT[(e4 + 1) * 40 + rv] = (short)f2bf(gv.y);
            vT[(e4 + 2) * 40 + rv] = (short)f2bf(gv.z);
            vT[(e4 + 3) * 40 + rv] = (short)f2bf(gv.w);
        }
    }
    for (int i4 = tid; i4 < 1024; i4 += 256) {
        int m_l = i4 >> 4, dq = i4 & 15;
        *(ushort4*)&projb[m_l * 72 + dq * 4] =
            pack4(*(const float4*)&proj[(mhf * 64 + m_l) * D + dq * 4]);
    }
    __syncthreads();

    // ---- proj MFMA: wave rt, 4 local m-tiles
    f32x4 accp[4];
#pragma unroll
    for (int i = 0; i < 4; i++) accp[i] = (f32x4){0.f, 0.f, 0.f, 0.f};
#pragma unroll
    for (int kt = 0; kt < 2; kt++) {
        short8 a = *(const short8*)&xb[(16 * rt + fr) * 72 + kt * 32 + fq * 8];
#pragma unroll
        for (int i = 0; i < 4; i++) {
            short8 bb = *(const short8*)&projb[(16 * i + fr) * 72 + kt * 32 + fq * 8];
            accp[i] = __builtin_amdgcn_mfma_f32_16x16x32_bf16(a, bb, accp[i], 0, 0, 0);
        }
    }
#pragma unroll
    for (int i = 0; i < 4; i++) {
#pragma unroll
        for (int reg = 0; reg < 4; reg++) {
            const int r = 16 * rt + fq * 4 + reg;
            const int m_l = 16 * i + fr;
            unsigned short bv = f2bf(fmaxf(accp[i][reg], 0.f) + EPS);
            obuf[r * 72 + m_l] = (short)bv;
            if (rt >= 2) kpT[m_l * 40 + (r - 32)] = (short)bv;
        }
    }
    __syncthreads();

    // ---- writeout qp/kp half (16B short8; obuf stride 144B is 16B-aligned)
    for (int i = tid; i < 512; i += 256) {
        int r = i >> 3, cu8 = i & 7;
        short8 val = *(const short8*)&obuf[r * 72 + cu8 * 8];
        unsigned short* g =
            (r < 32) ? &qpb[(rowbase + r) * M + mhf * 64 + cu8 * 8]
                     : &kpb[(rowbase + r - 32) * M + mhf * 64 + cu8 * 8];
        *(short8*)g = val;
    }
    // ---- kpart half: 4 lanes per m, shfl_xor reduce
    const int gb = h * 32 + rblk;
    {
        const int m_l = tid >> 2, qr = tid & 3;
        float part = 0.f;
#pragma unroll
        for (int r = 0; r < 8; r++)
            part += bf2f((unsigned short)kpT[m_l * 40 + qr * 8 + r]);
        float t2;
        t2 = __shfl_xor(part, 1, 4); part += t2;
        t2 = __shfl_xor(part, 2, 4); part += t2;
        if (qr == 0) kpart[gb * M + mhf * 64 + m_l] = part;
    }
    __syncthreads();

    // ---- G half: wave wv = m-tile (4 tiles of 16)
    f32x4 gacc[4];
#pragma unroll
    for (int et = 0; et < 4; et++) gacc[et] = (f32x4){0.f, 0.f, 0.f, 0.f};
    {
        short8 a = *(const short8*)&kpT[(16 * wv + fr) * 40 + fq * 8];
#pragma unroll
        for (int et = 0; et < 4; et++) {
            short8 bb = *(const short8*)&vT[(16 * et + fr) * 40 + fq * 8];
            gacc[et] = __builtin_amdgcn_mfma_f32_16x16x32_bf16(a, bb, gacc[et], 0, 0, 0);
        }
    }
#pragma unroll
    for (int et = 0; et < 4; et++)
#pragma unroll
        for (int reg = 0; reg < 4; reg++) {
            const int m_l = 16 * wv + fq * 4 + reg;
            obuf[m_l * 68 + 16 * et + fr] = (short)f2bf(gacc[et][reg]);
        }
    __syncthreads();
    for (int i = tid; i < 1024; i += 256) {
        int m_l = i >> 4, e4 = (i & 15) * 4;
        *(ushort4*)&Gpb[(gb * M + mhf * 64 + m_l) * D + e4] =
            *(const ushort4*)&obuf[m_l * 68 + e4];
    }
}

// -------- K1.5: s-granular prefixes. 512 blocks x 512 thr (as R20).
__global__ __launch_bounds__(512) void k_prefix(const float* __restrict__ kpart,
                                                const unsigned short* __restrict__ Gpb,
                                                float* __restrict__ zpre,
                                                unsigned short* __restrict__ S0pre) {
    const int tid = threadIdx.x;
    const int qr = tid & 3, s0 = qr * 8;
    const int eg = (blockIdx.x << 7) | (tid >> 2); // global element 0..65535
    const int h = eg >> 13, eb = eg & 8191;

    float g[8];
#pragma unroll
    for (int r = 0; r < 8; r++)
        g[r] = bf2f(Gpb[(h * 32 + s0 + r) * (M * D) + eb]);
    float part = 0.f;
#pragma unroll
    for (int r = 0; r < 8; r++) part += g[r];
    float incl = part, tt;
    tt = __shfl_up(incl, 1, 4); if (qr >= 1) incl += tt;
    tt = __shfl_up(incl, 2, 4); if (qr >= 2) incl += tt;
    tt = __shfl_up(incl, 1, 4); // inclusive sum of quarter qr-1
    float a = (qr == 0) ? 0.f : tt;
    unsigned short o[8];
#pragma unroll
    for (int r = 0; r < 8; r++) {
        o[r] = f2bf(a);
        a += g[r];
    }
#pragma unroll
    for (int r = 0; r < 8; r++)
        S0pre[(h * 32 + s0 + r) * (M * D) + eb] = o[r];

    if (blockIdx.x < 8) {
        const int hh = blockIdx.x;
        const int m = tid >> 2;
        float kv[8];
#pragma unroll
        for (int r = 0; r < 8; r++) kv[r] = kpart[(hh * 32 + s0 + r) * M + m];
        float p2 = 0.f;
#pragma unroll
        for (int r = 0; r < 8; r++) p2 += kv[r];
        float i2 = p2, t2;
        t2 = __shfl_up(i2, 1, 4); if (qr >= 1) i2 += t2;
        t2 = __shfl_up(i2, 2, 4); if (qr >= 2) i2 += t2;
        t2 = __shfl_up(i2, 1, 4);
        float z = (qr == 0) ? 0.f : t2;
#pragma unroll
        for (int r = 0; r < 8; r++) {
            zpre[(hh * 32 + s0 + r) * M + m] = z;
            z += kv[r];
        }
    }
}

// -------- K2 (R21): grid (256, 2 ehf), 256 thr. Block: 32 rows x 32 e-half.
// out = W @ S0pre[s] + tril(W @ Kp_own^T) @ V_own.
__global__ __launch_bounds__(256) void k_attn(const unsigned short* __restrict__ qpb,
                                              const unsigned short* __restrict__ kpb,
                                              const float* __restrict__ zpre,
                                              const unsigned short* __restrict__ S0pre,
                                              const float* __restrict__ v,
                                              float* __restrict__ out) {
    __shared__ __align__(16) short smem[19968]; // 39.9 KB -> 2 blocks/CU
    short* bufW = smem;          // W  [32 n][136]
    short* bufK = smem + 4352;   // Kp [32 j][136]
    short* bufQ = smem + 8704;   // qp [32 n][136]
    short* s0t  = smem + 13056;  // S0^T half [32 e_l][136] (m in columns)
    short* vT   = smem + 17408;  // V^T half  [32 e_l][40]  (j in columns)
    short* bufP = smem + 18688;  // Pb        [32 n][40]    (j in columns)
    const int tid = threadIdx.x;
    const int b = blockIdx.x;
    const int ehf = blockIdx.y;
    const int h = b >> 5, s = b & 31;
    const int rowstart = h * N + s * 32;
    const int lane = tid & 63, wv = tid >> 6;       // 4 waves
    const int rt = wv & 1, js = wv >> 1;            // 2x2 tile grid
    const int fr = lane & 15, fq = lane >> 4;

    // ---- straight-line global loads (issue all before LDS writes)
    short8 kpre[2], qpre[2];
#pragma unroll
    for (int t = 0; t < 2; t++) {
        const int i = tid + t * 256;
        const int sj = i >> 4, smu = i & 15;
        kpre[t] = *(const short8*)&kpb[(rowstart + sj) * M + smu * 8];
        qpre[t] = *(const short8*)&qpb[(rowstart + sj) * M + smu * 8];
    }
    const int pm = tid >> 1, pq = tid & 1;
    const unsigned short* s0src =
        &S0pre[(h * 32 + s) * (M * D) + pm * D + ehf * 32 + pq * 16];
    short8 s0a = *(const short8*)&s0src[0];
    short8 s0b = *(const short8*)&s0src[8];
    const int sj2 = tid >> 3, ve = (tid & 7) * 4;
    float4 gv = *(const float4*)&v[(rowstart + sj2) * D + ehf * 32 + ve];
    const int zm = tid >> 1, qh = tid & 1;
    const float zinit = zpre[(h * 32 + s) * M + zm];

    // ---- LDS writes
#pragma unroll
    for (int t = 0; t < 2; t++) {
        const int i = tid + t * 256;
        const int sj = i >> 4, smu = i & 15;
        *(short8*)&bufK[sj * 136 + smu * 8] = kpre[t];
        *(short8*)&bufQ[sj * 136 + smu * 8] = qpre[t];
    }
    {
        const int el = pq * 16;
#pragma unroll
        for (int j = 0; j < 8; j++) {
            s0t[(el + j) * 136 + pm] = s0a[j];
            s0t[(el + 8 + j) * 136 + pm] = s0b[j];
        }
    }
    vT[(ve + 0) * 40 + sj2] = (short)f2bf(gv.x);
    vT[(ve + 1) * 40 + sj2] = (short)f2bf(gv.y);
    vT[(ve + 2) * 40 + sj2] = (short)f2bf(gv.z);
    vT[(ve + 3) * 40 + sj2] = (short)f2bf(gv.w);
    __syncthreads(); // (1)

    // ---- z-scan -> W, 2 lanes per m-column (16 rows each + width-2 carry)
    {
        const int r0 = qh * 16;
        float kv[16];
        float part = 0.f;
#pragma unroll
        for (int r = 0; r < 16; r++) {
            kv[r] = bf2f((unsigned short)bufK[(r0 + r) * 136 + zm]);
            part += kv[r];
        }
        float ex = __shfl_up(part, 1, 2); // lane qh-1's partial
        float z = zinit + ((qh == 0) ? 0.f : ex);
#pragma unroll
        for (int r = 0; r < 16; r++) {
            const int rr = r0 + r;
            z += kv[r];
            bufW[rr * 136 + zm] = (short)f2bf(
                bf2f((unsigned short)bufQ[rr * 136 + zm]) *
                __builtin_amdgcn_rcpf(z));
        }
    }
    __syncthreads(); // (2) W ready

    // ---- P2a: out-half = W @ S0-half (K=128); wave (rt, js)
    f32x4 acc2 = (f32x4){0.f, 0.f, 0.f, 0.f};
#pragma unroll
    for (int kt = 0; kt < 4; kt++) {
        short8 a = *(const short8*)&bufW[(16 * rt + fr) * 136 + kt * 32 + fq * 8];
        short8 bb = *(const short8*)&s0t[(16 * js + fr) * 136 + kt * 32 + fq * 8];
        acc2 = __builtin_amdgcn_mfma_f32_16x16x32_bf16(a, bb, acc2, 0, 0, 0);
    }
    // ---- P1: Pb = tril(W @ Kp^T) — all 4 waves, tile (rt, jt = js)
    {
        const int jt = js;
        f32x4 acc1 = (f32x4){0.f, 0.f, 0.f, 0.f};
#pragma unroll
        for (int kt = 0; kt < 4; kt++) {
            short8 a = *(const short8*)&bufW[(16 * rt + fr) * 136 + kt * 32 + fq * 8];
            short8 bb = *(const short8*)&bufK[(16 * jt + fr) * 136 + kt * 32 + fq * 8];
            acc1 = __builtin_amdgcn_mfma_f32_16x16x32_bf16(a, bb, acc1, 0, 0, 0);
        }
        const int j = 16 * jt + fr;
#pragma unroll
        for (int reg = 0; reg < 4; reg++) {
            const int nloc = 16 * rt + fq * 4 + reg;
            float val = (j <= nloc) ? acc1[reg] : 0.f;
            bufP[nloc * 40 + j] = (short)f2bf(val);
        }
    }
    __syncthreads(); // (3) Pb ready

    // ---- P2b: out += P @ V-half (K=32)
    {
        short8 a = *(const short8*)&bufP[(16 * rt + fr) * 40 + fq * 8];
        short8 bb = *(const short8*)&vT[(16 * js + fr) * 40 + fq * 8];
        acc2 = __builtin_amdgcn_mfma_f32_16x16x32_bf16(a, bb, acc2, 0, 0, 0);
    }

    // ---- epilogue
#pragma unroll
    for (int reg = 0; reg < 4; reg++) {
        out[(rowstart + 16 * rt + fq * 4 + reg) * D + ehf * 32 + 16 * js + fr] =
            acc2[reg];
    }
}

extern "C" void kernel_launch(void* const* d_in, const int* in_sizes, int n_in,
                              void* d_out, int out_size, void* d_ws, size_t ws_size,
                              hipStream_t stream) {
    const float* q = (const float*)d_in[0];
    const float* k = (const float*)d_in[1];
    const float* v = (const float*)d_in[2];
    const float* proj = (const float*)d_in[3];
    float* out = (float*)d_out;

    // workspace: kpart 128KB fp32; qpb/kpb 2MB bf16 each; Gpb 4MB bf16;
    // zpre 128KB fp32; S0pre 4MB bf16 (s-granular)
    float* ws = (float*)d_ws;
    float* kpart = ws;                                           // H*32*M
    unsigned short* qpb = (unsigned short*)(kpart + H * 32 * M); // H*N*M
    unsigned short* kpb = qpb + H * N * M;                       // H*N*M
    unsigned short* Gpb = kpb + H * N * M;                       // H*32*M*D
    float* zpre = (float*)(Gpb + H * 32 * M * D);                // H*32*M
    unsigned short* S0pre = (unsigned short*)(zpre + H * 32 * M); // H*32*M*D

    k_projg<<<dim3(32, H, 2), 256, 0, stream>>>(q, k, proj, v, qpb, kpb, Gpb,
                                                kpart);
    k_prefix<<<dim3(512), 512, 0, stream>>>(kpart, Gpb, zpre, S0pre);
    k_attn<<<dim3(H * 32, 2), 256, 0, stream>>>(qpb, kpb, zpre, S0pre, v, out);
}

// Round 11
// 75.258 us; speedup vs baseline: 1.0243x; 1.0243x over previous
//
#include <hip/hip_runtime.h>

// Performer causal linear attention (generalized relu kernel), fp32 in/out.
// B=1, H=8, N=1024, D=64, M=128. Sub-block formulation, S=32 rows/block:
//   qp = relu(norm * q @ proj^T) + eps ; kp likewise
//   Z  = cumsum_n kp ; W = qp / Z
//   out_s = W_s @ S0_s + tril(W_s @ Kp_s^T) @ V_s ; S0_s = prefix of Kp^T V
// R23 = R18 restored verbatim (best measured: 75.6us). Experiment record:
//  - R16/R19: in-kernel cross-block sync (grid barrier / one-way flags)
//    costs +44/+20us vs kernel boundaries on MI355X (XCD L2 writeback +
//    poll serialization). 3 launches is the sync floor.
//  - R20 (deeper chain-parallelism) and R21 (2 blocks/CU via tile split):
//    both neutral-to-negative — bodies are irreducibly latency-bound at
//    this size (R16 measured 3-4% VALUBusy in these exact phase bodies).
// Remaining time: ~41us harness poison-fill (256MiB WRITE in timed stream,
// untouchable) + ~6-9us launch boundaries + ~25us latency-bound bodies.
static constexpr int H = 8, N = 1024, D = 64, M = 128;
static constexpr float EPS = 1e-3f;
static constexpr float NORM = 0.35355339059327373f; // 64^-0.25

typedef __attribute__((ext_vector_type(8))) short short8;
typedef __attribute__((ext_vector_type(4))) float f32x4;

__device__ inline unsigned short f2bf(float x) {
    unsigned u = __float_as_uint(x);
    return (unsigned short)((u + 0x7fffu + ((u >> 16) & 1u)) >> 16);
}
__device__ inline float bf2f(unsigned short u) {
    return __uint_as_float(((unsigned)u) << 16);
}
__device__ inline ushort4 pack4(float4 g) {
    return (ushort4){f2bf(g.x), f2bf(g.y), f2bf(g.z), f2bf(g.w)};
}

// -------- K1: qpb/kpb = bf16(relu(norm x @ proj^T)+eps), Gpb, kpart.
// grid (32 rblk, 8 h), 512 thr. One block: 32 rows of BOTH q and k.
__global__ __launch_bounds__(512) void k_projg(const float* __restrict__ q,
                                               const float* __restrict__ k,
                                               const float* __restrict__ proj,
                                               const float* __restrict__ v,
                                               unsigned short* __restrict__ qpb,
                                               unsigned short* __restrict__ kpb,
                                               unsigned short* __restrict__ Gpb,
                                               float* __restrict__ kpart) {
    __shared__ __align__(16) short smem[30208]; // 60.4 KB
    short* projb = smem;         // [m 128][72] B-operand
    short* xb = smem + 9216;     // [r 64][72] A-operand (q rows 0-31, k 32-63)
    short* obuf = smem + 13824;  // [64][136] out tile / later [128][68] G
    short* kpT = smem + 22528;   // [m 128][40] A-operand for G
    short* vT = smem + 27648;    // [e 64][40] B-operand for G
    const int tid = threadIdx.x;
    const int rblk = blockIdx.x;
    const int h = blockIdx.y;
    const int rowbase = h * N + rblk * 32;
    const int lane = tid & 63, wv = tid >> 6;
    const int rt = wv & 3, mh = wv >> 2;
    const int fr = lane & 15, fq = lane >> 4;

    // ---- front-load own q/k/v global loads (latency overlaps proj loop)
    {
        int r = tid >> 4, dq = tid & 15;
        float4 g = *(const float4*)&q[(rowbase + r) * D + dq * 4];
        float4 gk = *(const float4*)&k[(rowbase + r) * D + dq * 4];
        int rv = tid & 31, e4 = (tid >> 5) * 4;
        float4 gv = *(const float4*)&v[(rowbase + rv) * D + e4];
        g.x *= NORM; g.y *= NORM; g.z *= NORM; g.w *= NORM;
        *(ushort4*)&xb[r * 72 + dq * 4] = pack4(g);
        gk.x *= NORM; gk.y *= NORM; gk.z *= NORM; gk.w *= NORM;
        *(ushort4*)&xb[(32 + r) * 72 + dq * 4] = pack4(gk);
        vT[(e4 + 0) * 40 + rv] = (short)f2bf(gv.x);
        vT[(e4 + 1) * 40 + rv] = (short)f2bf(gv.y);
        vT[(e4 + 2) * 40 + rv] = (short)f2bf(gv.z);
        vT[(e4 + 3) * 40 + rv] = (short)f2bf(gv.w);
    }
    for (int i4 = tid; i4 < 2048; i4 += 512) {
        int m = i4 >> 4, dq = i4 & 15;
        *(ushort4*)&projb[m * 72 + dq * 4] = pack4(*(const float4*)&proj[i4 * 4]);
    }
    __syncthreads();

    f32x4 accp[4];
#pragma unroll
    for (int i = 0; i < 4; i++) accp[i] = (f32x4){0.f, 0.f, 0.f, 0.f};
#pragma unroll
    for (int kt = 0; kt < 2; kt++) {
        short8 a = *(const short8*)&xb[(16 * rt + fr) * 72 + kt * 32 + fq * 8];
#pragma unroll
        for (int i = 0; i < 4; i++) {
            const int mt = mh * 4 + i;
            short8 bb = *(const short8*)&projb[(16 * mt + fr) * 72 + kt * 32 + fq * 8];
            accp[i] = __builtin_amdgcn_mfma_f32_16x16x32_bf16(a, bb, accp[i], 0, 0, 0);
        }
    }
#pragma unroll
    for (int i = 0; i < 4; i++) {
        const int mt = mh * 4 + i;
#pragma unroll
        for (int reg = 0; reg < 4; reg++) {
            const int r = 16 * rt + fq * 4 + reg;
            const int m = 16 * mt + fr;
            unsigned short bv = f2bf(fmaxf(accp[i][reg], 0.f) + EPS);
            obuf[r * 136 + m] = (short)bv;
            if (rt >= 2) kpT[m * 40 + (r - 32)] = (short)bv;
        }
    }
    __syncthreads();

    // ---- writeout qp/kp as 16B short8 (row strides 272B / 256B, aligned)
    for (int i = tid; i < 1024; i += 512) {
        int r = i >> 4, cu8 = i & 15;
        short8 val = *(const short8*)&obuf[r * 136 + cu8 * 8];
        unsigned short* g = (r < 32) ? &qpb[(rowbase + r) * M + cu8 * 8]
                                     : &kpb[(rowbase + r - 32) * M + cu8 * 8];
        *(short8*)g = val;
    }
    const int gb = h * 32 + rblk;
    if (tid < 128) {
        float ks = 0.f;
#pragma unroll 8
        for (int r = 0; r < 32; r++) ks += bf2f((unsigned short)kpT[tid * 40 + r]);
        kpart[gb * M + tid] = ks;
    }
    __syncthreads();

    f32x4 gacc[4];
#pragma unroll
    for (int et = 0; et < 4; et++) gacc[et] = (f32x4){0.f, 0.f, 0.f, 0.f};
    {
        short8 a = *(const short8*)&kpT[(16 * wv + fr) * 40 + fq * 8];
#pragma unroll
        for (int et = 0; et < 4; et++) {
            short8 bb = *(const short8*)&vT[(16 * et + fr) * 40 + fq * 8];
            gacc[et] = __builtin_amdgcn_mfma_f32_16x16x32_bf16(a, bb, gacc[et], 0, 0, 0);
        }
    }
#pragma unroll
    for (int et = 0; et < 4; et++)
#pragma unroll
        for (int reg = 0; reg < 4; reg++) {
            const int m = 16 * wv + fq * 4 + reg;
            obuf[m * 68 + 16 * et + fr] = (short)f2bf(gacc[et][reg]);
        }
    __syncthreads();
    for (int i = tid; i < 2048; i += 512) {
        int m = i >> 4, e4 = (i & 15) * 4;
        *(ushort4*)&Gpb[(gb * M + m) * D + e4] = *(const ushort4*)&obuf[m * 68 + e4];
    }
}

// -------- K1.5: s-granular prefixes, 256 blocks x 256 thr.
// All 32 loads hoisted into registers (one vmcnt wait), then the fp32
// chain (order identical -> bit-identical S0pre), then 32 stores.
__global__ __launch_bounds__(256) void k_prefix(const float* __restrict__ kpart,
                                                const unsigned short* __restrict__ Gpb,
                                                float* __restrict__ zpre,
                                                unsigned short* __restrict__ S0pre) {
    const int h = blockIdx.x >> 5, seg = blockIdx.x & 31;
    const int tid = threadIdx.x;
    const int eb = seg * 256 + tid;
    float g[32];
#pragma unroll
    for (int s = 0; s < 32; s++)
        g[s] = bf2f(Gpb[(h * 32 + s) * (M * D) + eb]);
    float a = 0.f;
    unsigned short o[32];
#pragma unroll
    for (int s = 0; s < 32; s++) {
        o[s] = f2bf(a);
        a += g[s];
    }
#pragma unroll
    for (int s = 0; s < 32; s++)
        S0pre[(h * 32 + s) * (M * D) + eb] = o[s];

    if (seg == 0 && tid < 128) {
        float kv[32];
#pragma unroll
        for (int s = 0; s < 32; s++) kv[s] = kpart[(h * 32 + s) * M + tid];
        float z = 0.f;
        float zo[32];
#pragma unroll
        for (int s = 0; s < 32; s++) {
            zo[s] = z;
            z += kv[s];
        }
#pragma unroll
        for (int s = 0; s < 32; s++)
            zpre[(h * 32 + s) * M + tid] = zo[s];
    }
}

// -------- K2: grid (256), 512 thr. Every block identical: 32 output rows.
// out = W @ S0pre[s] + tril(W @ Kp_own^T) @ V_own.
__global__ __launch_bounds__(512) void k_attn(const unsigned short* __restrict__ qpb,
                                              const unsigned short* __restrict__ kpb,
                                              const float* __restrict__ zpre,
                                              const unsigned short* __restrict__ S0pre,
                                              const float* __restrict__ v,
                                              float* __restrict__ out) {
    __shared__ __align__(16) short smem[25600]; // 51.2 KB
    short* bufW = smem;          // W  [32 n][136]
    short* bufK = smem + 4352;   // Kp [32 j][136]
    short* bufQ = smem + 8704;   // qp [32 n][136]
    short* s0t  = smem + 13056;  // S0^T [64 e][136] (m in columns)
    short* vT   = smem + 21760;  // V^T  [64 e][40]  (j in columns)
    short* bufP = smem + 24320;  // Pb   [32 n][40]  (j in columns)
    const int tid = threadIdx.x;
    const int b = blockIdx.x;
    const int h = b >> 5, s = b & 31;
    const int rowstart = h * N + s * 32;
    const int lane = tid & 63, wv = tid >> 6;
    const int rt = wv & 1, js = wv >> 1;
    const int fr = lane & 15, fq = lane >> 4;

    // ---- straight-line global loads (all issue before any LDS write)
    const int sj = tid >> 4, smu = tid & 15; // kp/qp: row sj, 8-ushort grp smu
    short8 kpre = *(const short8*)&kpb[(rowstart + sj) * M + smu * 8];
    short8 qpre = *(const short8*)&qpb[(rowstart + sj) * M + smu * 8];
    const int pm = tid >> 2, peb = (tid & 3) * 16;
    const unsigned short* s0src = &S0pre[(h * 32 + s) * (M * D) + pm * D + peb];
    short8 s0a = *(const short8*)&s0src[0];
    short8 s0b = *(const short8*)&s0src[8];
    const int ve4 = (tid & 15) * 4;
    float4 gv = *(const float4*)&v[(rowstart + sj) * D + ve4];
    const float zinit = zpre[(h * 32 + s) * M + (tid >> 2)];

    // ---- LDS writes
    *(short8*)&bufK[sj * 136 + smu * 8] = kpre;
    *(short8*)&bufQ[sj * 136 + smu * 8] = qpre;
#pragma unroll
    for (int j = 0; j < 8; j++) {
        s0t[(peb + j) * 136 + pm] = s0a[j];
        s0t[(peb + 8 + j) * 136 + pm] = s0b[j];
    }
    vT[(ve4 + 0) * 40 + sj] = (short)f2bf(gv.x);
    vT[(ve4 + 1) * 40 + sj] = (short)f2bf(gv.y);
    vT[(ve4 + 2) * 40 + sj] = (short)f2bf(gv.z);
    vT[(ve4 + 3) * 40 + sj] = (short)f2bf(gv.w);
    __syncthreads(); // (1)

    // ---- z-scan -> W, 4-way parallel: thread (zm = tid>>2, qr = tid&3)
    {
        const int zm = tid >> 2, qr = tid & 3, r0 = qr * 8;
        float kv[8];
        float part = 0.f;
#pragma unroll
        for (int r = 0; r < 8; r++) {
            kv[r] = bf2f((unsigned short)bufK[(r0 + r) * 136 + zm]);
            part += kv[r];
        }
        float incl = part, t;
        t = __shfl_up(incl, 1, 4); if (qr >= 1) incl += t;
        t = __shfl_up(incl, 2, 4); if (qr >= 2) incl += t;
        t = __shfl_up(incl, 1, 4); // = inclusive sum of quarter qr-1
        float z = zinit + ((qr == 0) ? 0.f : t);
#pragma unroll
        for (int r = 0; r < 8; r++) {
            const int rr = r0 + r;
            z += kv[r];
            bufW[rr * 136 + zm] = (short)f2bf(
                bf2f((unsigned short)bufQ[rr * 136 + zm]) *
                __builtin_amdgcn_rcpf(z));
        }
    }
    __syncthreads(); // (2) W ready

    // ---- P2a: out = W @ S0 (K=128) — all 8 waves, tile (rt, js)
    f32x4 acc2 = (f32x4){0.f, 0.f, 0.f, 0.f};
#pragma unroll
    for (int kt = 0; kt < 4; kt++) {
        short8 a = *(const short8*)&bufW[(16 * rt + fr) * 136 + kt * 32 + fq * 8];
        short8 bb = *(const short8*)&s0t[(16 * js + fr) * 136 + kt * 32 + fq * 8];
        acc2 = __builtin_amdgcn_mfma_f32_16x16x32_bf16(a, bb, acc2, 0, 0, 0);
    }
    // ---- P1: Pb = tril(W @ Kp^T) — waves 0..3 only, tile (rt, jt)
    if (wv < 4) {
        const int jt = wv >> 1;
        f32x4 acc1 = (f32x4){0.f, 0.f, 0.f, 0.f};
#pragma unroll
        for (int kt = 0; kt < 4; kt++) {
            short8 a = *(const short8*)&bufW[(16 * rt + fr) * 136 + kt * 32 + fq * 8];
            short8 bb = *(const short8*)&bufK[(16 * jt + fr) * 136 + kt * 32 + fq * 8];
            acc1 = __builtin_amdgcn_mfma_f32_16x16x32_bf16(a, bb, acc1, 0, 0, 0);
        }
        const int j = 16 * jt + fr;
#pragma unroll
        for (int reg = 0; reg < 4; reg++) {
            const int nloc = 16 * rt + fq * 4 + reg;
            float val = (j <= nloc) ? acc1[reg] : 0.f;
            bufP[nloc * 40 + j] = (short)f2bf(val);
        }
    }
    __syncthreads(); // (3) Pb ready

    // ---- P2b: out += P @ V (K=32)
    {
        short8 a = *(const short8*)&bufP[(16 * rt + fr) * 40 + fq * 8];
        short8 bb = *(const short8*)&vT[(16 * js + fr) * 40 + fq * 8];
        acc2 = __builtin_amdgcn_mfma_f32_16x16x32_bf16(a, bb, acc2, 0, 0, 0);
    }

    // ---- epilogue
#pragma unroll
    for (int reg = 0; reg < 4; reg++) {
        out[(rowstart + 16 * rt + fq * 4 + reg) * D + 16 * js + fr] = acc2[reg];
    }
}

extern "C" void kernel_launch(void* const* d_in, const int* in_sizes, int n_in,
                              void* d_out, int out_size, void* d_ws, size_t ws_size,
                              hipStream_t stream) {
    const float* q = (const float*)d_in[0];
    const float* k = (const float*)d_in[1];
    const float* v = (const float*)d_in[2];
    const float* proj = (const float*)d_in[3];
    float* out = (float*)d_out;

    // workspace: kpart 128KB fp32; qpb/kpb 2MB bf16 each; Gpb 4MB bf16;
    // zpre 128KB fp32; S0pre 4MB bf16 (s-granular)
    float* ws = (float*)d_ws;
    float* kpart = ws;                                           // H*32*M
    unsigned short* qpb = (unsigned short*)(kpart + H * 32 * M); // H*N*M
    unsigned short* kpb = qpb + H * N * M;                       // H*N*M
    unsigned short* Gpb = kpb + H * N * M;                       // H*32*M*D
    float* zpre = (float*)(Gpb + H * 32 * M * D);                // H*32*M
    unsigned short* S0pre = (unsigned short*)(zpre + H * 32 * M); // H*32*M*D

    k_projg<<<dim3(32, H), 512, 0, stream>>>(q, k, proj, v, qpb, kpb, Gpb,
                                             kpart);
    k_prefix<<<dim3(256), 256, 0, stream>>>(kpart, Gpb, zpre, S0pre);
    k_attn<<<dim3(H * 32), 512, 0, stream>>>(qpb, kpb, zpre, S0pre, v, out);
}